// Round 1
// baseline (917.480 us; speedup 1.0000x reference)
//
#include <hip/hip_runtime.h>
#include <cstdint>
#include <cstddef>

// Problem constants (fixed by the reference)
#define S_TOK   8192
#define DMODEL  2048
#define NEXP    64
#define CAP     128
#define COMBINE_ELEMS 67108864ULL            // 8192*64*128
#define OUT_ELEMS     134217793ULL           // 1 + 2*COMBINE + 64
#define OUT_F4        33554448ULL            // floor(OUT_ELEMS/4); tail elem 134217792

#define GEMM_BLOCKS 256
#define SEL_BLOCKS  65                       // 64 expert-select + 1 finalize
#define ZERO_BASE   (GEMM_BLOCKS + SEL_BLOCKS)   // 321
#define ZERO_BLOCKS 4096
#define TOTAL_BLOCKS (ZERO_BASE + ZERO_BLOCKS)   // 4417
#define MAXN 2048

typedef float floatx4 __attribute__((ext_vector_type(4)));  // nontemporal-compatible

// jax.random.uniform(key(42)): JAX >= 0.5 threefry_partitionable path:
// bits[idx] = o0 ^ o1 of threefry2x32((0,42), (0, idx))
__device__ __forceinline__ unsigned rotl32(unsigned x, unsigned r) {
    return (x << r) | (x >> (32u - r));
}

__device__ __forceinline__ void threefry2x32(unsigned k0, unsigned k1,
                                             unsigned c0, unsigned c1,
                                             unsigned& o0, unsigned& o1) {
    unsigned ks[3] = {k0, k1, k0 ^ k1 ^ 0x1BD11BDAu};
    unsigned x0 = c0 + ks[0];
    unsigned x1 = c1 + ks[1];
    const unsigned rotA[4] = {13u, 15u, 26u, 6u};
    const unsigned rotB[4] = {17u, 29u, 16u, 24u};
#pragma unroll
    for (int i = 0; i < 5; ++i) {
        const unsigned* rr = (i & 1) ? rotB : rotA;
#pragma unroll
        for (int j = 0; j < 4; ++j) {
            x0 += x1;
            x1 = rotl32(x1, rr[j]);
            x1 ^= x0;
        }
        x0 += ks[(i + 1) % 3];
        x1 += ks[(i + 2) % 3] + (unsigned)(i + 1);
    }
    o0 = x0; o1 = x1;
}

__device__ __forceinline__ float jax_uniform_noise(unsigned idx) {
    unsigned o0, o1;
    threefry2x32(0u, 42u, 0u, idx, o0, o1);
    unsigned bits = o0 ^ o1;
    unsigned fb = (bits >> 9) | 0x3f800000u;
    float f;
    __builtin_memcpy(&f, &fb, 4);
    return f - 1.0f;
}

// LDS is role-dependent; union keeps the footprint at the GEMM role's 26.6 KB
// (6 blocks/CU, 12 waves/CU — same occupancy as the previous 2-kernel version).
struct SMemG { float xs[32][68]; float wsh[64][68]; float mep[2][64]; };
struct SMemS { int toks[MAXN]; float noi[MAXN]; int rnk[MAXN];
               unsigned long long obase[CAP]; float oval[CAP]; int n; int m; };
struct SMemF { int hist[NEXP]; };
union __align__(16) SMem { SMemG g; SMemS s; SMemF f; };

__device__ __forceinline__ void wait_ctr(const unsigned* __restrict__ p, unsigned target) {
    // one poller per block; relaxed agent-scope load observes remote device-scope
    // atomicAdds (coherent path), s_sleep limits poll rate / L2 pressure.
    if (threadIdx.x == 0) {
        while (__hip_atomic_load(p, __ATOMIC_RELAXED, __HIP_MEMORY_SCOPE_AGENT) < target)
            __builtin_amdgcn_s_sleep(32);
        __threadfence();   // acquire: invalidate stale L1/L2 before data reads
    }
    __syncthreads();
}

// ------ Single fused kernel ------
// blockIdx [0,256)    : GEMM 32tok x 64exp tile + in-block softmax/argmax; emits
//                       tok_expert/tok_gate/tok_noise + me_part; release-adds ctr[0].
// blockIdx [256,320)  : per-expert select: spin on ctr[0]==256 (GEMM done, ~40us in,
//                       hidden under the fill), scan+rank+loc, precompute scatter
//                       pairs in LDS, spin on ctr[1]==4096 (fill done), tiny scatter.
// blockIdx 320        : finalize: spin ctr[0], histogram + me reduce (bit-exact
//                       serial order), spin ctr[1], write l_aux + exp_counts.
// blockIdx [321,4417) : zero-fill d_out (537 MB) with nontemporal float4 stores;
//                       release-adds ctr[1]. This is the duration floor (~90us).
__global__ __launch_bounds__(128) void moe_fused(const float* __restrict__ x,
                                                 const float* __restrict__ wg,
                                                 unsigned* __restrict__ ctr,
                                                 int* __restrict__ tok_expert,
                                                 float* __restrict__ tok_gate,
                                                 float* __restrict__ tok_noise,
                                                 float* __restrict__ me_part,
                                                 float* __restrict__ d_out) {
    __shared__ SMem sm;
    const int tid = threadIdx.x;
    const unsigned bid = blockIdx.x;

    // ---------------- zero-fill role ----------------
    if (bid >= ZERO_BASE) {
        const size_t zb = bid - ZERO_BASE;
        floatx4* o4 = (floatx4*)d_out;
        const floatx4 z = {0.f, 0.f, 0.f, 0.f};
        const size_t stride = (size_t)ZERO_BLOCKS * 128;
        for (size_t i = zb * 128 + tid; i < OUT_F4; i += stride)
            __builtin_nontemporal_store(z, &o4[i]);
        if (zb == 0 && tid == 0) d_out[OUT_ELEMS - 1] = 0.f;  // tail elem (overwritten by finalize)
        __syncthreads();                       // all stores vmcnt-drained
        if (tid == 0) { __threadfence(); atomicAdd(&ctr[1], 1u); }  // release
        return;
    }

    // ---------------- GEMM + softmax role ----------------
    if (bid < GEMM_BLOCKS) {
        const int s0 = bid * 32;
        const int g  = tid & 15;          // experts g, g+16, g+32, g+48
        const int ty = tid >> 4;          // tokens ty*4 .. ty*4+3
        float acc[4][4];
#pragma unroll
        for (int i = 0; i < 4; ++i)
#pragma unroll
            for (int j = 0; j < 4; ++j) acc[i][j] = 0.f;

        for (int k0 = 0; k0 < DMODEL; k0 += 64) {
#pragma unroll
            for (int i = 0; i < 4; ++i) {  // x chunk: 32x64 = 512 float4, 128 thr
                int slot = tid + i * 128;
                int r = slot >> 4, c4 = (slot & 15) * 4;
                float4 v = *(const float4*)&x[(size_t)(s0 + r) * DMODEL + k0 + c4];
                *(float4*)&sm.g.xs[r][c4] = v;
            }
#pragma unroll
            for (int i = 0; i < 8; ++i) {  // wg chunk: 64x64 = 1024 float4
                int slot = tid + i * 128;
                int r = slot >> 4, c4 = (slot & 15) * 4;
                float4 v = *(const float4*)&wg[(size_t)r * DMODEL + k0 + c4];
                *(float4*)&sm.g.wsh[r][c4] = v;
            }
            __syncthreads();
#pragma unroll
            for (int k4 = 0; k4 < 64; k4 += 4) {
                float4 xv[4], wv[4];
#pragma unroll
                for (int t = 0; t < 4; ++t) xv[t] = *(float4*)&sm.g.xs[ty * 4 + t][k4];
#pragma unroll
                for (int j = 0; j < 4; ++j) wv[j] = *(float4*)&sm.g.wsh[g + 16 * j][k4];
#pragma unroll
                for (int t = 0; t < 4; ++t)
#pragma unroll
                    for (int j = 0; j < 4; ++j) {
                        // k-ascending chain per output: bit-identical across rounds
                        acc[t][j] += xv[t].x * wv[j].x; acc[t][j] += xv[t].y * wv[j].y;
                        acc[t][j] += xv[t].z * wv[j].z; acc[t][j] += xv[t].w * wv[j].w;
                    }
            }
            __syncthreads();
        }

        // ---- in-block softmax: park logits tile in xs (all xs reads are done) ----
#pragma unroll
        for (int t = 0; t < 4; ++t)
#pragma unroll
            for (int j = 0; j < 4; ++j)
                sm.g.xs[ty * 4 + t][g + 16 * j] = acc[t][j];
        __syncthreads();

        const int lane = tid & 63;        // lane == expert
        const int w = tid >> 6;           // wave handles tokens w*16 .. w*16+15
        float me_acc = 0.f;
#pragma unroll
        for (int it = 0; it < 16; ++it) {
            const int trow = w * 16 + it;
            float v = sm.g.xs[trow][lane];
            float m = v;
#pragma unroll
            for (int off = 32; off; off >>= 1) m = fmaxf(m, __shfl_xor(m, off));
            float ev = expf(v - m);
            float sum = ev;
#pragma unroll
            for (int off = 32; off; off >>= 1) sum += __shfl_xor(sum, off);
            float gate = ev / sum;
            me_acc += gate;

            float bv = gate; int bi = lane;
#pragma unroll
            for (int off = 32; off; off >>= 1) {
                float ov = __shfl_xor(bv, off);
                int   oi = __shfl_xor(bi, off);
                if (ov > bv || (ov == bv && oi < bi)) { bv = ov; bi = oi; }
            }
            if (lane == 0) {
                const int s = s0 + trow;
                tok_expert[s] = bi;
                tok_gate[s]   = bv;
                tok_noise[s]  = jax_uniform_noise((unsigned)(s * NEXP + bi));
            }
        }
        sm.g.mep[w][lane] = me_acc;
        __syncthreads();
        if (tid < 64)
            me_part[(size_t)bid * 64 + tid] = sm.g.mep[0][tid] + sm.g.mep[1][tid];
        __syncthreads();                       // all block writes vmcnt-drained
        if (tid == 0) { __threadfence(); atomicAdd(&ctr[0], 1u); }  // release
        return;
    }

    // ---------------- select / finalize roles (overlap under the fill) ----------------
    wait_ctr(&ctr[0], GEMM_BLOCKS);            // GEMM results visible

    if (bid == GEMM_BLOCKS + NEXP) {           // ---- finalize ----
        if (tid < NEXP) sm.f.hist[tid] = 0;
        __syncthreads();
        for (int s = tid; s < S_TOK; s += 128)
            atomicAdd(&sm.f.hist[tok_expert[s]], 1);
        __syncthreads();
        float laux = 0.f, cnt = 0.f;
        if (tid < 64) {
            const int e = tid;
            float me = 0.f;
            for (int b = 0; b < GEMM_BLOCKS; ++b) me += me_part[(size_t)b * 64 + e];  // serial: bit-exact
            me /= (float)S_TOK;
            int c = sm.f.hist[e];
            cnt = (float)c;
            float p = me * ((float)c / (float)S_TOK);
#pragma unroll
            for (int off = 32; off; off >>= 1) p += __shfl_xor(p, off);
            laux = p * (float)NEXP;
        }
        wait_ctr(&ctr[1], ZERO_BLOCKS);        // fill done -> safe to write head/tail
        if (tid < 64) d_out[1 + 2 * COMBINE_ELEMS + tid] = cnt;
        if (tid == 0) d_out[0] = laux;
        return;
    }

    // ---- per-expert top-capacity select ----
    const int e = (int)bid - GEMM_BLOCKS;
    if (tid == 0) { sm.s.n = 0; sm.s.m = 0; }
    __syncthreads();

    for (int s = tid; s < S_TOK; s += 128) {
        if (tok_expert[s] == e) {
            int i = atomicAdd(&sm.s.n, 1);
            if (i < MAXN) { sm.s.toks[i] = s; sm.s.noi[i] = tok_noise[s]; }
        }
    }
    __syncthreads();
    int n = sm.s.n; if (n > MAXN) n = MAXN;

    // rank by noise desc, ties -> lower token index (lax.top_k stability)
    for (int i = tid; i < n; i += 128) {
        float vi = sm.s.noi[i]; int si = sm.s.toks[i];
        int r = 0;
        for (int j = 0; j < n; ++j) {
            float vj = sm.s.noi[j];
            r += (vj > vi) || (vj == vi && sm.s.toks[j] < si);
        }
        sm.s.rnk[i] = r;
    }
    __syncthreads();

    // precompute scatter pairs (<=128) in LDS, BEFORE waiting on the fill
    for (int i = tid; i < n; i += 128) {
        if (sm.s.rnk[i] < CAP) {
            int si = sm.s.toks[i];
            int loc = 0;  // cumsum slot among kept tokens, by token index
            for (int j = 0; j < n; ++j)
                loc += (sm.s.rnk[j] < CAP) && (sm.s.toks[j] < si);
            int k = atomicAdd(&sm.s.m, 1);
            sm.s.obase[k] = 1ULL + (((size_t)si * NEXP + e) * CAP + (size_t)loc);
            sm.s.oval[k]  = tok_gate[si];
        }
    }
    __syncthreads();

    wait_ctr(&ctr[1], ZERO_BLOCKS);            // zeros landed & flushed -> scatter tail
    const int m = sm.s.m;
    for (int k = tid; k < m; k += 128) {
        size_t b = sm.s.obase[k];
        d_out[b] = sm.s.oval[k];               // combine_weights
        d_out[b + COMBINE_ELEMS] = 1.0f;       // dispatch_mask
    }
}

// ws is poisoned each iteration -> counters must be zeroed before the fused kernel.
__global__ void init_ctr(unsigned* __restrict__ ctr) {
    ctr[threadIdx.x] = 0u;
}

extern "C" void kernel_launch(void* const* d_in, const int* in_sizes, int n_in,
                              void* d_out, int out_size, void* d_ws, size_t ws_size,
                              hipStream_t stream) {
    const float* x  = (const float*)d_in[0];
    const float* wg = (const float*)d_in[1];
    float* out = (float*)d_out;
    float* ws  = (float*)d_ws;

    // ws layout (float offsets); all regions written before read each launch.
    unsigned* ctr      = (unsigned*)ws;     // [0]=gemm-done, [1]=zero-done (own 128B line)
    int*   tok_expert  = (int*)(ws + 64);   // 8192
    float* tok_gate    = ws + 64 + 8192;    // 8192
    float* tok_noise   = ws + 64 + 16384;   // 8192
    float* me_part     = ws + 64 + 24576;   // 256*64

    init_ctr<<<1, 2, 0, stream>>>(ctr);
    moe_fused<<<TOTAL_BLOCKS, 128, 0, stream>>>(x, wg, ctr, tok_expert, tok_gate,
                                                tok_noise, me_part, out);
}

// Round 2
// 677.942 us; speedup vs baseline: 1.3533x; 1.3533x over previous
//
#include <hip/hip_runtime.h>
#include <cstdint>
#include <cstddef>

// Problem constants (fixed by the reference)
#define S_TOK   8192
#define DMODEL  2048
#define NEXP    64
#define CAP     128
#define COMBINE_ELEMS 67108864ULL            // 8192*64*128
#define OUT_ELEMS     134217793ULL           // 1 + 2*COMBINE + 64

// jax.random.uniform(key(42)): JAX >= 0.5 threefry_partitionable path:
// bits[idx] = o0 ^ o1 of threefry2x32((0,42), (0, idx))
__device__ __forceinline__ unsigned rotl32(unsigned x, unsigned r) {
    return (x << r) | (x >> (32u - r));
}

__device__ __forceinline__ void threefry2x32(unsigned k0, unsigned k1,
                                             unsigned c0, unsigned c1,
                                             unsigned& o0, unsigned& o1) {
    unsigned ks[3] = {k0, k1, k0 ^ k1 ^ 0x1BD11BDAu};
    unsigned x0 = c0 + ks[0];
    unsigned x1 = c1 + ks[1];
    const unsigned rotA[4] = {13u, 15u, 26u, 6u};
    const unsigned rotB[4] = {17u, 29u, 16u, 24u};
#pragma unroll
    for (int i = 0; i < 5; ++i) {
        const unsigned* rr = (i & 1) ? rotB : rotA;
#pragma unroll
        for (int j = 0; j < 4; ++j) {
            x0 += x1;
            x1 = rotl32(x1, rr[j]);
            x1 ^= x0;
        }
        x0 += ks[(i + 1) % 3];
        x1 += ks[(i + 2) % 3] + (unsigned)(i + 1);
    }
    o0 = x0; o1 = x1;
}

__device__ __forceinline__ float jax_uniform_noise(unsigned idx) {
    unsigned o0, o1;
    threefry2x32(0u, 42u, 0u, idx, o0, o1);
    unsigned bits = o0 ^ o1;
    unsigned fb = (bits >> 9) | 0x3f800000u;
    float f;
    __builtin_memcpy(&f, &fb, 4);
    return f - 1.0f;
}

// ------ Kernel 1: logits GEMM + softmax/argmax (round-0 code, fill branch removed;
// the 537 MB output clear now goes through hipMemsetAsync -> runtime fillBuffer
// path, which sustains ~6.2 TB/s vs ~1-2 TB/s for our in-kernel nt-store fill). ------
#define GEMM_BLOCKS 256
__global__ __launch_bounds__(128) void gemm_softmax(const float* __restrict__ x,
                                                    const float* __restrict__ wg,
                                                    int* __restrict__ tok_expert,
                                                    float* __restrict__ tok_gate,
                                                    float* __restrict__ tok_noise,
                                                    float* __restrict__ me_part) {
    __shared__ __align__(16) float xs[32][68];   // doubles as logits tile post-GEMM
    __shared__ __align__(16) float wsh[64][68];
    __shared__ float mep[2][64];
    const int tid = threadIdx.x;
    const int s0 = blockIdx.x * 32;
    const int g  = tid & 15;          // experts g, g+16, g+32, g+48
    const int ty = tid >> 4;          // tokens ty*4 .. ty*4+3
    float acc[4][4];
#pragma unroll
    for (int i = 0; i < 4; ++i)
#pragma unroll
        for (int j = 0; j < 4; ++j) acc[i][j] = 0.f;

    for (int k0 = 0; k0 < DMODEL; k0 += 64) {
#pragma unroll
        for (int i = 0; i < 4; ++i) {  // x chunk: 32x64 = 512 float4, 128 thr
            int slot = tid + i * 128;
            int r = slot >> 4, c4 = (slot & 15) * 4;
            float4 v = *(const float4*)&x[(size_t)(s0 + r) * DMODEL + k0 + c4];
            *(float4*)&xs[r][c4] = v;
        }
#pragma unroll
        for (int i = 0; i < 8; ++i) {  // wg chunk: 64x64 = 1024 float4
            int slot = tid + i * 128;
            int r = slot >> 4, c4 = (slot & 15) * 4;
            float4 v = *(const float4*)&wg[(size_t)r * DMODEL + k0 + c4];
            *(float4*)&wsh[r][c4] = v;
        }
        __syncthreads();
#pragma unroll
        for (int k4 = 0; k4 < 64; k4 += 4) {
            float4 xv[4], wv[4];
#pragma unroll
            for (int t = 0; t < 4; ++t) xv[t] = *(float4*)&xs[ty * 4 + t][k4];
#pragma unroll
            for (int j = 0; j < 4; ++j) wv[j] = *(float4*)&wsh[g + 16 * j][k4];
#pragma unroll
            for (int t = 0; t < 4; ++t)
#pragma unroll
                for (int j = 0; j < 4; ++j) {
                    // k-ascending chain per output: bit-identical across rounds
                    acc[t][j] += xv[t].x * wv[j].x; acc[t][j] += xv[t].y * wv[j].y;
                    acc[t][j] += xv[t].z * wv[j].z; acc[t][j] += xv[t].w * wv[j].w;
                }
        }
        __syncthreads();
    }

    // ---- in-block softmax: park logits tile in xs (all xs reads are done) ----
#pragma unroll
    for (int t = 0; t < 4; ++t)
#pragma unroll
        for (int j = 0; j < 4; ++j)
            xs[ty * 4 + t][g + 16 * j] = acc[t][j];
    __syncthreads();

    const int lane = tid & 63;        // lane == expert
    const int w = tid >> 6;           // wave handles tokens w*16 .. w*16+15
    float me_acc = 0.f;
#pragma unroll
    for (int it = 0; it < 16; ++it) {
        const int trow = w * 16 + it;
        float v = xs[trow][lane];
        float m = v;
#pragma unroll
        for (int off = 32; off; off >>= 1) m = fmaxf(m, __shfl_xor(m, off));
        float ev = expf(v - m);
        float sum = ev;
#pragma unroll
        for (int off = 32; off; off >>= 1) sum += __shfl_xor(sum, off);
        float gate = ev / sum;
        me_acc += gate;

        float bv = gate; int bi = lane;
#pragma unroll
        for (int off = 32; off; off >>= 1) {
            float ov = __shfl_xor(bv, off);
            int   oi = __shfl_xor(bi, off);
            if (ov > bv || (ov == bv && oi < bi)) { bv = ov; bi = oi; }
        }
        if (lane == 0) {
            const int s = s0 + trow;
            tok_expert[s] = bi;
            tok_gate[s]   = bv;
            tok_noise[s]  = jax_uniform_noise((unsigned)(s * NEXP + bi));
        }
    }
    mep[w][lane] = me_acc;
    __syncthreads();
    if (tid < 64)
        me_part[(size_t)blockIdx.x * 64 + tid] = mep[0][tid] + mep[1][tid];
}

// ---- Kernel 2: blocks 0..63 per-expert top-capacity select + scatter;
// ---- block 64: self-sufficient finalize (own LDS histogram + me_part reduce).
// Unchanged from the round-0 known-good version (absmax 0).
#define MAXN 2048
__global__ __launch_bounds__(256) void select_finalize(const int* __restrict__ tok_expert,
                                                       const float* __restrict__ tok_gate,
                                                       const float* __restrict__ tok_noise,
                                                       const float* __restrict__ me_part,
                                                       float* __restrict__ d_out) {
    if (blockIdx.x == NEXP) {
        __shared__ int hist[NEXP];
        if (threadIdx.x < NEXP) hist[threadIdx.x] = 0;
        __syncthreads();
        for (int s = threadIdx.x; s < S_TOK; s += 256)
            atomicAdd(&hist[tok_expert[s]], 1);
        __syncthreads();
        if (threadIdx.x < 64) {
            const int e = threadIdx.x;
            float me = 0.f;
            for (int b = 0; b < 256; ++b) me += me_part[(size_t)b * 64 + e];
            me /= (float)S_TOK;
            int c = hist[e];
            float ce = (float)c / (float)S_TOK;
            float p = me * ce;
#pragma unroll
            for (int off = 32; off; off >>= 1) p += __shfl_xor(p, off);
            if (e == 0) d_out[0] = p * (float)NEXP;
            d_out[1 + 2 * COMBINE_ELEMS + e] = (float)c;
        }
        return;
    }

    const int e = blockIdx.x;
    __shared__ int   toks[MAXN];
    __shared__ float noi[MAXN];
    __shared__ int   rnk[MAXN];
    __shared__ int   n_sh;
    if (threadIdx.x == 0) n_sh = 0;
    __syncthreads();

    for (int s = threadIdx.x; s < S_TOK; s += 256) {
        if (tok_expert[s] == e) {
            int i = atomicAdd(&n_sh, 1);
            if (i < MAXN) { toks[i] = s; noi[i] = tok_noise[s]; }
        }
    }
    __syncthreads();
    int n = n_sh; if (n > MAXN) n = MAXN;

    // rank by noise desc, ties -> lower token index (lax.top_k stability)
    for (int i = threadIdx.x; i < n; i += 256) {
        float vi = noi[i]; int si = toks[i];
        int r = 0;
        for (int j = 0; j < n; ++j) {
            float vj = noi[j];
            r += (vj > vi) || (vj == vi && toks[j] < si);
        }
        rnk[i] = r;
    }
    __syncthreads();

    for (int i = threadIdx.x; i < n; i += 256) {
        if (rnk[i] < CAP) {
            int si = toks[i];
            int loc = 0;  // cumsum slot among kept tokens, by token index
            for (int j = 0; j < n; ++j)
                loc += (rnk[j] < CAP) && (toks[j] < si);
            size_t base = 1ULL + (((size_t)si * NEXP + e) * CAP + (size_t)loc);
            d_out[base] = tok_gate[si];              // combine_weights
            d_out[base + COMBINE_ELEMS] = 1.0f;      // dispatch_mask
        }
    }
}

extern "C" void kernel_launch(void* const* d_in, const int* in_sizes, int n_in,
                              void* d_out, int out_size, void* d_ws, size_t ws_size,
                              hipStream_t stream) {
    const float* x  = (const float*)d_in[0];
    const float* wg = (const float*)d_in[1];
    float* out = (float*)d_out;
    float* ws  = (float*)d_ws;

    // ws layout (float offsets); all regions fully written each launch.
    int*   tok_expert = (int*)ws;           // 8192
    float* tok_gate   = ws + 8192;          // 8192
    float* tok_noise  = ws + 16384;         // 8192
    float* me_part    = ws + 24576;         // 256*64

    // K1: GEMM+softmax writes only ws (independent of the output clear).
    gemm_softmax<<<GEMM_BLOCKS, 128, 0, stream>>>(x, wg, tok_expert, tok_gate,
                                                  tok_noise, me_part);

    // Output clear via the runtime fill path (~6.2 TB/s measured on this chip for
    // fillBufferAligned, vs ~1-2 TB/s for our in-kernel nontemporal-store fill).
    // Capture-legal: memset nodes are supported in HIP graphs (the harness's own
    // reset() enqueues hipMemsetAsync).
    hipMemsetAsync(out, 0, OUT_ELEMS * sizeof(float), stream);

    // K2: scatters the sparse nonzeros over the cleared output.
    select_finalize<<<NEXP + 1, 256, 0, stream>>>(tok_expert, tok_gate, tok_noise,
                                                  me_part, out);
}

// Round 3
// 651.235 us; speedup vs baseline: 1.4088x; 1.0410x over previous
//
#include <hip/hip_runtime.h>
#include <cstdint>
#include <cstddef>

// Problem constants (fixed by the reference)
#define S_TOK   8192
#define DMODEL  2048
#define NEXP    64
#define CAP     128
#define COMBINE_ELEMS 67108864ULL            // 8192*64*128
#define OUT_ELEMS     134217793ULL           // 1 + 2*COMBINE + 64
#define OUT_F4        33554448ULL            // floor(OUT_ELEMS/4); tail elem 134217792

// jax.random.uniform(key(42)): JAX >= 0.5 threefry_partitionable path:
// bits[idx] = o0 ^ o1 of threefry2x32((0,42), (0, idx))
__device__ __forceinline__ unsigned rotl32(unsigned x, unsigned r) {
    return (x << r) | (x >> (32u - r));
}

__device__ __forceinline__ void threefry2x32(unsigned k0, unsigned k1,
                                             unsigned c0, unsigned c1,
                                             unsigned& o0, unsigned& o1) {
    unsigned ks[3] = {k0, k1, k0 ^ k1 ^ 0x1BD11BDAu};
    unsigned x0 = c0 + ks[0];
    unsigned x1 = c1 + ks[1];
    const unsigned rotA[4] = {13u, 15u, 26u, 6u};
    const unsigned rotB[4] = {17u, 29u, 16u, 24u};
#pragma unroll
    for (int i = 0; i < 5; ++i) {
        const unsigned* rr = (i & 1) ? rotB : rotA;
#pragma unroll
        for (int j = 0; j < 4; ++j) {
            x0 += x1;
            x1 = rotl32(x1, rr[j]);
            x1 ^= x0;
        }
        x0 += ks[(i + 1) % 3];
        x1 += ks[(i + 2) % 3] + (unsigned)(i + 1);
    }
    o0 = x0; o1 = x1;
}

__device__ __forceinline__ float jax_uniform_noise(unsigned idx) {
    unsigned o0, o1;
    threefry2x32(0u, 42u, 0u, idx, o0, o1);
    unsigned bits = o0 ^ o1;
    unsigned fb = (bits >> 9) | 0x3f800000u;
    float f;
    __builtin_memcpy(&f, &fb, 4);
    return f - 1.0f;
}

// ------ Kernel 1: fused d_out zero-fill + logits GEMM + softmax/argmax ------
// blockIdx < 256  : GEMM block (128 thr): tile 32 tokens x 64 experts, BK=64,
//                   thread = 4 tok x 4 exp; then in-block softmax via LDS reuse,
//                   emits tok_expert/tok_gate/tok_noise + me_part[block][e].
// blockIdx >= 256 : zero-fill blocks. CHANGED vs round 0: PLAIN float4 stores
//                   (not __builtin_nontemporal_store) over a CONTIGUOUS 128 KB
//                   chunk per block — the fillBufferAligned / m13 recipe that
//                   measures 6.2-6.3 TB/s on this chip, vs 1.18 TB/s measured
//                   for our nt-store fill (round-1 counters: 575 MB / 486 us).
#define GEMM_BLOCKS 256
#define ZERO_BLOCKS 4096
#define CHUNK_F4    8192ULL                  // f4 per zero block (128 KB)
__global__ __launch_bounds__(128) void gemm_softmax_zero(const float* __restrict__ x,
                                                         const float* __restrict__ wg,
                                                         int* __restrict__ tok_expert,
                                                         float* __restrict__ tok_gate,
                                                         float* __restrict__ tok_noise,
                                                         float* __restrict__ me_part,
                                                         float* __restrict__ d_out) {
    if (blockIdx.x >= GEMM_BLOCKS) {
        const size_t zb = blockIdx.x - GEMM_BLOCKS;
        float4* o4 = (float4*)d_out;
        const float4 z = {0.f, 0.f, 0.f, 0.f};
        // contiguous chunk [zb*8192, (zb+1)*8192) f4; last block also covers the
        // 16-f4 remainder (OUT_F4 = 4096*8192 + 16) and the tail scalar element.
        const size_t lo = zb * CHUNK_F4;
        const size_t hi = (zb == ZERO_BLOCKS - 1) ? OUT_F4 : (zb + 1) * CHUNK_F4;
        for (size_t i = lo + threadIdx.x; i < hi; i += 128)
            o4[i] = z;
        if (zb == ZERO_BLOCKS - 1 && threadIdx.x == 0) d_out[OUT_ELEMS - 1] = 0.f;
        return;
    }

    __shared__ __align__(16) float xs[32][68];   // doubles as logits tile post-GEMM
    __shared__ __align__(16) float wsh[64][68];
    __shared__ float mep[2][64];
    const int tid = threadIdx.x;
    const int s0 = blockIdx.x * 32;
    const int g  = tid & 15;          // experts g, g+16, g+32, g+48
    const int ty = tid >> 4;          // tokens ty*4 .. ty*4+3
    float acc[4][4];
#pragma unroll
    for (int i = 0; i < 4; ++i)
#pragma unroll
        for (int j = 0; j < 4; ++j) acc[i][j] = 0.f;

    for (int k0 = 0; k0 < DMODEL; k0 += 64) {
#pragma unroll
        for (int i = 0; i < 4; ++i) {  // x chunk: 32x64 = 512 float4, 128 thr
            int slot = tid + i * 128;
            int r = slot >> 4, c4 = (slot & 15) * 4;
            float4 v = *(const float4*)&x[(size_t)(s0 + r) * DMODEL + k0 + c4];
            *(float4*)&xs[r][c4] = v;
        }
#pragma unroll
        for (int i = 0; i < 8; ++i) {  // wg chunk: 64x64 = 1024 float4
            int slot = tid + i * 128;
            int r = slot >> 4, c4 = (slot & 15) * 4;
            float4 v = *(const float4*)&wg[(size_t)r * DMODEL + k0 + c4];
            *(float4*)&wsh[r][c4] = v;
        }
        __syncthreads();
#pragma unroll
        for (int k4 = 0; k4 < 64; k4 += 4) {
            float4 xv[4], wv[4];
#pragma unroll
            for (int t = 0; t < 4; ++t) xv[t] = *(float4*)&xs[ty * 4 + t][k4];
#pragma unroll
            for (int j = 0; j < 4; ++j) wv[j] = *(float4*)&wsh[g + 16 * j][k4];
#pragma unroll
            for (int t = 0; t < 4; ++t)
#pragma unroll
                for (int j = 0; j < 4; ++j) {
                    // k-ascending chain per output: bit-identical across rounds
                    acc[t][j] += xv[t].x * wv[j].x; acc[t][j] += xv[t].y * wv[j].y;
                    acc[t][j] += xv[t].z * wv[j].z; acc[t][j] += xv[t].w * wv[j].w;
                }
        }
        __syncthreads();
    }

    // ---- in-block softmax: park logits tile in xs (all xs reads are done) ----
#pragma unroll
    for (int t = 0; t < 4; ++t)
#pragma unroll
        for (int j = 0; j < 4; ++j)
            xs[ty * 4 + t][g + 16 * j] = acc[t][j];
    __syncthreads();

    const int lane = tid & 63;        // lane == expert
    const int w = tid >> 6;           // wave handles tokens w*16 .. w*16+15
    float me_acc = 0.f;
#pragma unroll
    for (int it = 0; it < 16; ++it) {
        const int trow = w * 16 + it;
        float v = xs[trow][lane];
        float m = v;
#pragma unroll
        for (int off = 32; off; off >>= 1) m = fmaxf(m, __shfl_xor(m, off));
        float ev = expf(v - m);
        float sum = ev;
#pragma unroll
        for (int off = 32; off; off >>= 1) sum += __shfl_xor(sum, off);
        float gate = ev / sum;
        me_acc += gate;

        float bv = gate; int bi = lane;
#pragma unroll
        for (int off = 32; off; off >>= 1) {
            float ov = __shfl_xor(bv, off);
            int   oi = __shfl_xor(bi, off);
            if (ov > bv || (ov == bv && oi < bi)) { bv = ov; bi = oi; }
        }
        if (lane == 0) {
            const int s = s0 + trow;
            tok_expert[s] = bi;
            tok_gate[s]   = bv;
            tok_noise[s]  = jax_uniform_noise((unsigned)(s * NEXP + bi));
        }
    }
    mep[w][lane] = me_acc;
    __syncthreads();
    if (tid < 64)
        me_part[(size_t)blockIdx.x * 64 + tid] = mep[0][tid] + mep[1][tid];
}

// ---- Kernel 2: blocks 0..63 per-expert top-capacity select + scatter;
// ---- block 64: self-sufficient finalize (own LDS histogram + me_part reduce).
// Unchanged from the round-0 known-good version (absmax 0).
#define MAXN 2048
__global__ __launch_bounds__(256) void select_finalize(const int* __restrict__ tok_expert,
                                                       const float* __restrict__ tok_gate,
                                                       const float* __restrict__ tok_noise,
                                                       const float* __restrict__ me_part,
                                                       float* __restrict__ d_out) {
    if (blockIdx.x == NEXP) {
        __shared__ int hist[NEXP];
        if (threadIdx.x < NEXP) hist[threadIdx.x] = 0;
        __syncthreads();
        for (int s = threadIdx.x; s < S_TOK; s += 256)
            atomicAdd(&hist[tok_expert[s]], 1);
        __syncthreads();
        if (threadIdx.x < 64) {
            const int e = threadIdx.x;
            float me = 0.f;
            for (int b = 0; b < 256; ++b) me += me_part[(size_t)b * 64 + e];
            me /= (float)S_TOK;
            int c = hist[e];
            float ce = (float)c / (float)S_TOK;
            float p = me * ce;
#pragma unroll
            for (int off = 32; off; off >>= 1) p += __shfl_xor(p, off);
            if (e == 0) d_out[0] = p * (float)NEXP;
            d_out[1 + 2 * COMBINE_ELEMS + e] = (float)c;
        }
        return;
    }

    const int e = blockIdx.x;
    __shared__ int   toks[MAXN];
    __shared__ float noi[MAXN];
    __shared__ int   rnk[MAXN];
    __shared__ int   n_sh;
    if (threadIdx.x == 0) n_sh = 0;
    __syncthreads();

    for (int s = threadIdx.x; s < S_TOK; s += 256) {
        if (tok_expert[s] == e) {
            int i = atomicAdd(&n_sh, 1);
            if (i < MAXN) { toks[i] = s; noi[i] = tok_noise[s]; }
        }
    }
    __syncthreads();
    int n = n_sh; if (n > MAXN) n = MAXN;

    // rank by noise desc, ties -> lower token index (lax.top_k stability)
    for (int i = threadIdx.x; i < n; i += 256) {
        float vi = noi[i]; int si = toks[i];
        int r = 0;
        for (int j = 0; j < n; ++j) {
            float vj = noi[j];
            r += (vj > vi) || (vj == vi && toks[j] < si);
        }
        rnk[i] = r;
    }
    __syncthreads();

    for (int i = threadIdx.x; i < n; i += 256) {
        if (rnk[i] < CAP) {
            int si = toks[i];
            int loc = 0;  // cumsum slot among kept tokens, by token index
            for (int j = 0; j < n; ++j)
                loc += (rnk[j] < CAP) && (toks[j] < si);
            size_t base = 1ULL + (((size_t)si * NEXP + e) * CAP + (size_t)loc);
            d_out[base] = tok_gate[si];              // combine_weights
            d_out[base + COMBINE_ELEMS] = 1.0f;      // dispatch_mask
        }
    }
}

extern "C" void kernel_launch(void* const* d_in, const int* in_sizes, int n_in,
                              void* d_out, int out_size, void* d_ws, size_t ws_size,
                              hipStream_t stream) {
    const float* x  = (const float*)d_in[0];
    const float* wg = (const float*)d_in[1];
    float* out = (float*)d_out;
    float* ws  = (float*)d_ws;

    // ws layout (float offsets); all regions fully written each launch, no memsets.
    int*   tok_expert = (int*)ws;           // 8192
    float* tok_gate   = ws + 8192;          // 8192
    float* tok_noise  = ws + 16384;         // 8192
    float* me_part    = ws + 24576;         // 256*64

    gemm_softmax_zero<<<GEMM_BLOCKS + ZERO_BLOCKS, 128, 0, stream>>>(
        x, wg, tok_expert, tok_gate, tok_noise, me_part, out);
    select_finalize<<<NEXP + 1, 256, 0, stream>>>(tok_expert, tok_gate, tok_noise,
                                                  me_part, out);
}